// Round 6
// baseline (575.921 us; speedup 1.0000x reference)
//
#include <hip/hip_runtime.h>

#define Bn 8
#define Tn 4096
#define Dn 256
#define Mn (Bn*Tn)           // 32768

typedef short bf16x8 __attribute__((ext_vector_type(8)));
typedef float f32x4 __attribute__((ext_vector_type(4)));
typedef float f32x16 __attribute__((ext_vector_type(16)));

// ---- ws layout (bytes) ----
// phase A: wt @16 MB (384 KB)
// phase B: partials bf16 @0 (40 MB = 640 slots * 64 KB), ml float2 @41943040 (640 KB)
// persistent: qkv (Q, K, V^T bf16) @42598400 (48 MB)  -> total ~88.6 MB (proven fits)
#define P_OFF   0ul
#define ML_OFF  41943040ul
#define WT_OFF  16777216ul
#define QKV_OFF 42598400ul

__device__ __forceinline__ unsigned short f2bf(float f) {
    union { float f; unsigned int u; } v; v.f = f;
    unsigned int r = v.u + 0x7fffu + ((v.u >> 16) & 1u);
    return (unsigned short)(r >> 16);
}
__device__ __forceinline__ float bf2f(unsigned short u) {
    union { unsigned int u; float f; } v; v.u = ((unsigned int)u) << 16;
    return v.f;
}
__device__ __forceinline__ unsigned int pk2(float a, float b) {
    return (unsigned int)f2bf(a) | ((unsigned int)f2bf(b) << 16);
}

typedef __attribute__((address_space(1))) const unsigned int* gas_p;
typedef __attribute__((address_space(3))) unsigned int* las_p;
__device__ __forceinline__ void g2lds16(const void* g, void* l) {
    __builtin_amdgcn_global_load_lds((gas_p)g, (las_p)l, 16, 0, 0);
}

// ---------------- W transpose+cast ----------------
__global__ void __launch_bounds__(256) wt_kernel(const float* __restrict__ wq,
                                                 const float* __restrict__ wk,
                                                 const float* __restrict__ wv,
                                                 unsigned short* __restrict__ wt) {
    int idx = blockIdx.x * 256 + threadIdx.x;
    int h = idx >> 16; int r = idx & 65535;
    int k = r >> 8, n = r & 255;
    const float* src = (h == 0) ? wq : (h == 1) ? wk : wv;
    wt[h * 65536 + n * 256 + k] = f2bf(src[k * 256 + n]);
}

// ---------------- projection GEMM (x f32 read + inline cast) ----------------
// h=0: Q row-major; h=1: K row-major; h=2: V transposed [256][M]
__global__ void __launch_bounds__(256, 2) proj_kernel(const float* __restrict__ x,
                                                      const unsigned short* __restrict__ wt,
                                                      unsigned short* __restrict__ qkv) {
    __shared__ unsigned short wlds[256 * 40];
    int h = blockIdx.y;
    const unsigned short* wth = wt + h * 65536;
    int m0 = blockIdx.x * 64;
    int tid = threadIdx.x;
    int w = tid >> 6, lane = tid & 63;
    int c = lane & 15, g = lane >> 4;
    size_t arow = (size_t)(m0 + w * 16 + c);

    const f32x4 fz = {0.f, 0.f, 0.f, 0.f};
    f32x4 acc[16];
#pragma unroll
    for (int n = 0; n < 16; n++) acc[n] = fz;

    for (int kk = 0; kk < 8; kk++) {
        __syncthreads();
#pragma unroll
        for (int p = 0; p < 4; p++) {
            int idx = p * 256 + tid;
            int r = idx >> 2, ch = idx & 3;
            bf16x8 v = *(const bf16x8*)(wth + r * 256 + kk * 32 + ch * 8);
            *(bf16x8*)(&wlds[r * 40 + ch * 8]) = v;
        }
        __syncthreads();
        const float4* xa = (const float4*)(x + arow * Dn + kk * 32 + g * 8);
        float4 a0 = xa[0], a1 = xa[1];
        union { unsigned short u[8]; bf16x8 v; } af;
        af.u[0]=f2bf(a0.x); af.u[1]=f2bf(a0.y); af.u[2]=f2bf(a0.z); af.u[3]=f2bf(a0.w);
        af.u[4]=f2bf(a1.x); af.u[5]=f2bf(a1.y); af.u[6]=f2bf(a1.z); af.u[7]=f2bf(a1.w);
#pragma unroll
        for (int n = 0; n < 16; n++) {
            bf16x8 bfv = *(const bf16x8*)(&wlds[(n * 16 + c) * 40 + g * 8]);
            acc[n] = __builtin_amdgcn_mfma_f32_16x16x32_bf16(af.v, bfv, acc[n], 0, 0, 0);
        }
    }
    int orow0 = m0 + w * 16 + g * 4;
    if (h < 2) {
        unsigned short* out = qkv + (size_t)h * Mn * Dn;
#pragma unroll
        for (int n = 0; n < 16; n++)
#pragma unroll
            for (int r = 0; r < 4; r++)
                out[(size_t)(orow0 + r) * Dn + n * 16 + c] = f2bf(acc[n][r]);
    } else {
        unsigned short* vt = qkv + (size_t)2 * Mn * Dn;   // [256][M]
#pragma unroll
        for (int n = 0; n < 16; n++) {
            union { unsigned short u[4]; ushort4 v4; } pk;
#pragma unroll
            for (int r = 0; r < 4; r++) pk.u[r] = f2bf(acc[n][r]);
            *(ushort4*)(vt + (size_t)(n * 16 + c) * Mn + orow0) = pk.v4;
        }
    }
}

// ---------------- attention: 32x32x16 swapped, 128-row q-tiles, KV-split ----------------
// 640 blocks, bid = r*8+b. Mapping as round 5. K double-buffered, V single-buffered.
__global__ void __launch_bounds__(256, 3) attn_kernel(const unsigned short* __restrict__ qkv,
                                                      unsigned short* __restrict__ part,
                                                      float2* __restrict__ ml) {
    __shared__ char smem[49152];   // K dbuf 2x16KB @0, V 16KB @32768

    int bid = blockIdx.x;
    int b = bid & 7;
    int r = bid >> 3;
    int qtp, cc;
    if (r < 24)      { qtp = 24 + (r & 7); cc = r >> 3; }
    else if (r < 40) { int rp = r - 24; qtp = 16 + (rp & 7); cc = rp >> 3; }
    else if (r < 48) { qtp = 8 + (r - 40); cc = 0; }
    else             { int k = r - 48; int u = k >> 2, v = k & 3; qtp = 8 * v + 7 - u; cc = v; }
    int slot = b * 80 + r;

    int tid = threadIdx.x, w = tid >> 6, lane = tid & 63;
    int lq = lane & 31, hh = lane >> 5;

    const unsigned short* Qg = qkv;
    const unsigned short* Kg = qkv + (size_t)Mn * Dn;
    const unsigned short* Vt = qkv + (size_t)2 * Mn * Dn;

    int qrow = qtp * 128 + w * 32 + lq;

    bf16x8 qf[16];
#pragma unroll
    for (int s = 0; s < 16; s++)
        qf[s] = *(const bf16x8*)(Qg + ((size_t)b * Tn + qrow) * Dn + s * 16 + hh * 8);

    f32x16 o[8];
#pragma unroll
    for (int dg = 0; dg < 8; dg++)
#pragma unroll
        for (int e = 0; e < 16; e++) o[dg][e] = 0.f;
    float m2 = -INFINITY, lsum = 0.f;

    const float C1 = 0.09016844005555897f;       // (1/16) * log2(e)

    auto STAGE_K = [&](int cb, int t) {
        const unsigned short* kgb = Kg + ((size_t)b * Tn + t * 32) * Dn;
        char* kb = smem + cb * 16384 + w * 4096;
#pragma unroll
        for (int i = 0; i < 4; i++) {
            int row = w * 8 + i * 2 + hh;
            int chunk = lq ^ row;
            g2lds16(kgb + row * 256 + chunk * 8, kb + i * 1024);
        }
    };
    auto STAGE_V = [&](int t) {
        const unsigned short* vgb = Vt + (size_t)b * Tn + t * 32;
        char* vb = smem + 32768 + w * 4096;
#pragma unroll
        for (int i = 0; i < 4; i++) {
            int d = w * 64 + i * 16 + (lane >> 2);
            int kvc = (lane & 3) ^ ((d >> 3) & 3);
            g2lds16(vgb + (size_t)d * Mn + kvc * 8, vb + i * 1024);
        }
    };

    union U4 { unsigned int u[4]; bf16x8 v; };
    U4 fr[2];

    auto QKSM = [&](int cb, int t) {
        int kv0 = t * 32;
        const char* klds = smem + cb * 16384;
        // ---- S^T = K Q^T, two independent chains ----
        f32x16 sva, svb;
#pragma unroll
        for (int e = 0; e < 16; e++) { sva[e] = 0.f; svb[e] = 0.f; }
        __builtin_amdgcn_s_setprio(1);
#pragma unroll
        for (int s = 0; s < 8; s++) {
            bf16x8 kfa = *(const bf16x8*)(klds + lq * 512 + ((2 * s + hh) ^ lq) * 16);
            sva = __builtin_amdgcn_mfma_f32_32x32x16_bf16(kfa, qf[s], sva, 0, 0, 0);
            bf16x8 kfb = *(const bf16x8*)(klds + lq * 512 + ((2 * (s + 8) + hh) ^ lq) * 16);
            svb = __builtin_amdgcn_mfma_f32_32x32x16_bf16(kfb, qf[s + 8], svb, 0, 0, 0);
        }
        __builtin_amdgcn_s_setprio(0);
        f32x16 sv = sva + svb;
        // ---- mask + scale (exp2 domain) ----
        float pv[16];
        float tmax = -INFINITY;
#pragma unroll
        for (int rr = 0; rr < 16; rr++) {
            int kvl = kv0 + (rr & 3) + 8 * (rr >> 2) + 4 * hh;
            float v = sv[rr] * C1;
            v = (kvl <= qrow) ? v : -INFINITY;
            pv[rr] = v;
            tmax = fmaxf(tmax, v);
        }
        tmax = fmaxf(tmax, __shfl_xor(tmax, 32));
        float mn = m2;
        if (!__all(tmax - m2 <= 8.0f)) {          // T13 defer-max
            mn = fmaxf(m2, tmax);
            float alpha = exp2f(m2 - mn);
            lsum *= alpha;
            m2 = mn;
#pragma unroll
            for (int dg = 0; dg < 8; dg++) o[dg] = o[dg] * alpha;
        }
        float ps = 0.f;
#pragma unroll
        for (int rr = 0; rr < 16; rr++) {
            pv[rr] = exp2f(pv[rr] - mn);
            ps += pv[rr];
        }
        ps += __shfl_xor(ps, 32);
        lsum += ps;
        // ---- P^T B-fragments (source-side select + xor32 exchange) ----
#pragma unroll
        for (int s2 = 0; s2 < 2; s2++) {
            int bidx = 8 * s2;
            unsigned int w0 = pk2(pv[bidx + 0], pv[bidx + 1]);
            unsigned int w1 = pk2(pv[bidx + 2], pv[bidx + 3]);
            unsigned int y0 = pk2(pv[bidx + 4], pv[bidx + 5]);
            unsigned int y1 = pk2(pv[bidx + 6], pv[bidx + 7]);
            unsigned int e0 = hh ? w0 : y0;
            unsigned int e1 = hh ? w1 : y1;
            unsigned int x0 = (unsigned int)__shfl_xor((int)e0, 32);
            unsigned int x1 = (unsigned int)__shfl_xor((int)e1, 32);
            fr[s2].u[0] = hh ? x0 : w0;
            fr[s2].u[1] = hh ? x1 : w1;
            fr[s2].u[2] = hh ? y0 : x0;
            fr[s2].u[3] = hh ? y1 : x1;
        }
    };

    auto PV = [&]() {
        const char* vlds = smem + 32768;
        __builtin_amdgcn_s_setprio(1);
#pragma unroll
        for (int dg = 0; dg < 8; dg++) {
            int d = 32 * dg + lq;
            int swz = (d >> 3) & 3;
#pragma unroll
            for (int s2 = 0; s2 < 2; s2++) {
                bf16x8 vf = *(const bf16x8*)(vlds + d * 64 + ((2 * s2 + hh) ^ swz) * 16);
                o[dg] = __builtin_amdgcn_mfma_f32_32x32x16_bf16(vf, fr[s2].v, o[dg], 0, 0, 0);
            }
        }
        __builtin_amdgcn_s_setprio(0);
    };

    int t0 = cc * 32;
    int tend = min(t0 + 32, 4 * (qtp + 1));
    int cb = 0;
    STAGE_K(0, t0);
    STAGE_V(t0);
    __syncthreads();
    for (int t = t0; t < tend; t++) {
        if (t + 1 < tend) STAGE_K(cb ^ 1, t + 1);
        QKSM(cb, t);
        __syncthreads();          // drains V(t) (+K(t+1), covered by QK+softmax)
        PV();
        if (t + 1 < tend) {
            __syncthreads();      // V buffer free for overwrite
            STAGE_V(t + 1);
        }
        cb ^= 1;
    }

    // ---- m,l ----
    if (hh == 0)
        ml[(size_t)slot * 128 + w * 32 + lq] = make_float2(m2, lsum);

    // ---- partial store (register-native packed layout) ----
    uint4* pb = (uint4*)part;
#pragma unroll
    for (int dg = 0; dg < 8; dg++) {
        uint4 lo, hi2;
        lo.x = pk2(o[dg][0], o[dg][1]);  lo.y = pk2(o[dg][2], o[dg][3]);
        lo.z = pk2(o[dg][4], o[dg][5]);  lo.w = pk2(o[dg][6], o[dg][7]);
        hi2.x = pk2(o[dg][8], o[dg][9]);  hi2.y = pk2(o[dg][10], o[dg][11]);
        hi2.z = pk2(o[dg][12], o[dg][13]); hi2.w = pk2(o[dg][14], o[dg][15]);
        size_t base = (size_t)slot * 4096 + w * 1024 + dg * 128 + lane;
        pb[base] = lo;
        pb[base + 64] = hi2;
    }
}

// ---------------- combine ----------------
__global__ void __launch_bounds__(256) combine_kernel(const unsigned short* __restrict__ part,
                                                      const float2* __restrict__ ml,
                                                      float* __restrict__ out) {
    __shared__ float2 mls[4][32];
    int bid = blockIdx.x;
    int b = bid & 7;
    int rest = bid >> 3;
    int qtp = rest >> 2, w = rest & 3;
    int nch = (qtp >> 3) + 1;
    int tid = threadIdx.x;

    int slots[4];
#pragma unroll
    for (int ci = 0; ci < 4; ci++) {
        int rr;
        if (ci == nch - 1)       rr = 48 + 4 * (7 - (qtp & 7)) + (qtp >> 3);
        else if (qtp >= 24)      rr = 8 * ci + (qtp - 24);
        else if (qtp >= 16)      rr = 24 + 8 * ci + (qtp - 16);
        else                     rr = 40 + (qtp - 8);
        slots[ci] = b * 80 + rr;
    }
    if (tid < nch * 32) {
        int ci = tid >> 5, qq = tid & 31;
        mls[ci][qq] = ml[(size_t)slots[ci] * 128 + w * 32 + qq];
    }
    __syncthreads();

    int dg = tid >> 5, h2 = (tid >> 4) & 1, ls = tid & 15;
    const uint4* pb = (const uint4*)part;

    for (int rd = 0; rd < 4; rd++) {
        int lane_idx = ls + 16 * rd;
        int q = lane_idx & 31, hh = lane_idx >> 5;
        float M = -INFINITY;
#pragma unroll
        for (int ci = 0; ci < 4; ci++)
            if (ci < nch) M = fmaxf(M, mls[ci][q].x);
        float L = 0.f, wgt[4];
#pragma unroll
        for (int ci = 0; ci < 4; ci++) {
            if (ci < nch) { wgt[ci] = exp2f(mls[ci][q].x - M); L += wgt[ci] * mls[ci][q].y; }
            else wgt[ci] = 0.f;
        }
        float inv = 1.f / L;
        float a[8];
#pragma unroll
        for (int e = 0; e < 8; e++) a[e] = 0.f;
#pragma unroll
        for (int ci = 0; ci < 4; ci++) {
            if (ci >= nch) break;
            uint4 u = pb[(size_t)slots[ci] * 4096 + w * 1024 + dg * 128 + h2 * 64 + lane_idx];
            float wg = wgt[ci];
            a[0] += wg * bf2f((unsigned short)(u.x & 0xffff));
            a[1] += wg * bf2f((unsigned short)(u.x >> 16));
            a[2] += wg * bf2f((unsigned short)(u.y & 0xffff));
            a[3] += wg * bf2f((unsigned short)(u.y >> 16));
            a[4] += wg * bf2f((unsigned short)(u.z & 0xffff));
            a[5] += wg * bf2f((unsigned short)(u.z >> 16));
            a[6] += wg * bf2f((unsigned short)(u.w & 0xffff));
            a[7] += wg * bf2f((unsigned short)(u.w >> 16));
        }
        size_t row = (size_t)b * Tn + qtp * 128 + w * 32 + q;
        int dbase = 32 * dg + 16 * h2 + 4 * hh;
        float4 A = {a[0] * inv, a[1] * inv, a[2] * inv, a[3] * inv};
        float4 Bv = {a[4] * inv, a[5] * inv, a[6] * inv, a[7] * inv};
        *(float4*)(out + row * 256 + dbase) = A;
        *(float4*)(out + row * 256 + dbase + 8) = Bv;
    }
}

extern "C" void kernel_launch(void* const* d_in, const int* in_sizes, int n_in,
                              void* d_out, int out_size, void* d_ws, size_t ws_size,
                              hipStream_t stream) {
    (void)in_sizes; (void)n_in; (void)out_size; (void)ws_size;
    const float* x  = (const float*)d_in[0];
    const float* wk = (const float*)d_in[1];
    const float* wq = (const float*)d_in[2];
    const float* wv = (const float*)d_in[3];
    float* outp = (float*)d_out;

    char* ws = (char*)d_ws;
    unsigned short* wt   = (unsigned short*)(ws + WT_OFF);
    unsigned short* qkv  = (unsigned short*)(ws + QKV_OFF);
    unsigned short* part = (unsigned short*)(ws + P_OFF);
    float2*         mlp  = (float2*)(ws + ML_OFF);

    wt_kernel<<<3 * 65536 / 256, 256, 0, stream>>>(wq, wk, wv, wt);
    proj_kernel<<<dim3(Mn / 64, 3), 256, 0, stream>>>(x, wt, qkv);
    attn_kernel<<<640, 256, 0, stream>>>(qkv, part, mlp);
    combine_kernel<<<1024, 256, 0, stream>>>(part, mlp, outp);
}

// Round 7
// 212.586 us; speedup vs baseline: 2.7091x; 2.7091x over previous
//
#include <hip/hip_runtime.h>

#define Bn 8
#define Tn 4096
#define Dn 256
#define Mn (Bn*Tn)           // 32768

typedef short bf16x8 __attribute__((ext_vector_type(8)));
typedef float f32x4 __attribute__((ext_vector_type(4)));

// ---- ws layout (bytes) ----
// phase A: wt @16 MB (384 KB)
// phase B: partials bf16 @0 (40 MB = 1280 slots * 32 KB), ml float2 @41943040 (640 KB)
// persistent: qkv (Q, K, V^T bf16) @42598400 (48 MB)  -> ~88.6 MB total (proven fits)
#define P_OFF   0ul
#define ML_OFF  41943040ul
#define WT_OFF  16777216ul
#define QKV_OFF 42598400ul

__device__ __forceinline__ unsigned short f2bf(float f) {
    union { float f; unsigned int u; } v; v.f = f;
    unsigned int r = v.u + 0x7fffu + ((v.u >> 16) & 1u);
    return (unsigned short)(r >> 16);
}
__device__ __forceinline__ float bf2f(unsigned short u) {
    union { unsigned int u; float f; } v; v.u = ((unsigned int)u) << 16;
    return v.f;
}
__device__ __forceinline__ unsigned int pk2(float a, float b) {
    return (unsigned int)f2bf(a) | ((unsigned int)f2bf(b) << 16);
}

typedef __attribute__((address_space(1))) const unsigned int* gas_p;
typedef __attribute__((address_space(3))) unsigned int* las_p;
__device__ __forceinline__ void g2lds16(const void* g, void* l) {
    __builtin_amdgcn_global_load_lds((gas_p)g, (las_p)l, 16, 0, 0);
}

// ---------------- W transpose+cast ----------------
__global__ void __launch_bounds__(256) wt_kernel(const float* __restrict__ wq,
                                                 const float* __restrict__ wk,
                                                 const float* __restrict__ wv,
                                                 unsigned short* __restrict__ wt) {
    int idx = blockIdx.x * 256 + threadIdx.x;
    int h = idx >> 16; int r = idx & 65535;
    int k = r >> 8, n = r & 255;
    const float* src = (h == 0) ? wq : (h == 1) ? wk : wv;
    wt[h * 65536 + n * 256 + k] = f2bf(src[k * 256 + n]);
}

// ---------------- projection GEMM (x f32 read + inline cast) ----------------
// h=0: Q row-major; h=1: K row-major; h=2: V transposed [256][M]
__global__ void __launch_bounds__(256, 2) proj_kernel(const float* __restrict__ x,
                                                      const unsigned short* __restrict__ wt,
                                                      unsigned short* __restrict__ qkv) {
    __shared__ unsigned short wlds[256 * 40];
    int h = blockIdx.y;
    const unsigned short* wth = wt + h * 65536;
    int m0 = blockIdx.x * 64;
    int tid = threadIdx.x;
    int w = tid >> 6, lane = tid & 63;
    int c = lane & 15, g = lane >> 4;
    size_t arow = (size_t)(m0 + w * 16 + c);

    const f32x4 fz = {0.f, 0.f, 0.f, 0.f};
    f32x4 acc[16];
#pragma unroll
    for (int n = 0; n < 16; n++) acc[n] = fz;

    for (int kk = 0; kk < 8; kk++) {
        __syncthreads();
#pragma unroll
        for (int p = 0; p < 4; p++) {
            int idx = p * 256 + tid;
            int r = idx >> 2, ch = idx & 3;
            bf16x8 v = *(const bf16x8*)(wth + r * 256 + kk * 32 + ch * 8);
            *(bf16x8*)(&wlds[r * 40 + ch * 8]) = v;
        }
        __syncthreads();
        const float4* xa = (const float4*)(x + arow * Dn + kk * 32 + g * 8);
        float4 a0 = xa[0], a1 = xa[1];
        union { unsigned short u[8]; bf16x8 v; } af;
        af.u[0]=f2bf(a0.x); af.u[1]=f2bf(a0.y); af.u[2]=f2bf(a0.z); af.u[3]=f2bf(a0.w);
        af.u[4]=f2bf(a1.x); af.u[5]=f2bf(a1.y); af.u[6]=f2bf(a1.z); af.u[7]=f2bf(a1.w);
#pragma unroll
        for (int n = 0; n < 16; n++) {
            bf16x8 bfv = *(const bf16x8*)(&wlds[(n * 16 + c) * 40 + g * 8]);
            acc[n] = __builtin_amdgcn_mfma_f32_16x16x32_bf16(af.v, bfv, acc[n], 0, 0, 0);
        }
    }
    int orow0 = m0 + w * 16 + g * 4;
    if (h < 2) {
        unsigned short* out = qkv + (size_t)h * Mn * Dn;
#pragma unroll
        for (int n = 0; n < 16; n++)
#pragma unroll
            for (int r = 0; r < 4; r++)
                out[(size_t)(orow0 + r) * Dn + n * 16 + c] = f2bf(acc[n][r]);
    } else {
        unsigned short* vt = qkv + (size_t)2 * Mn * Dn;   // [256][M]
#pragma unroll
        for (int n = 0; n < 16; n++) {
            union { unsigned short u[4]; ushort4 v4; } pk;
#pragma unroll
            for (int r = 0; r < 4; r++) pk.u[r] = f2bf(acc[n][r]);
            *(ushort4*)(vt + (size_t)(n * 16 + c) * Mn + orow0) = pk.v4;
        }
    }
}

// ---------------- attention: 16x16x32 swapped, 64-row q-tiles, KV-split ----------------
// 1280 blocks: bid = 8r + b. r in [0,160): chunk cc via offsets {0,64,112,144}; j = r - off;
// qt = 63 - j (heavy first). Tiles [32cc, min(32cc+32, 2qt+2)), KVBLK=32.
// K double-buffered (2x16KB), V single-buffered (16KB): 48KB -> 3 blocks/CU.
__global__ void __launch_bounds__(256, 3) attn_kernel(const unsigned short* __restrict__ qkv,
                                                      unsigned short* __restrict__ part,
                                                      float2* __restrict__ ml) {
    __shared__ char smem[49152];

    int bid = blockIdx.x;
    int b = bid & 7;
    int r = bid >> 3;             // 0..159
    int cc, j;
    if (r < 64)       { cc = 0; j = r; }
    else if (r < 112) { cc = 1; j = r - 64; }
    else if (r < 144) { cc = 2; j = r - 112; }
    else              { cc = 3; j = r - 144; }
    int qt = 63 - j;
    int slot = b * 160 + r;
    int q0 = qt * 64;

    int tid = threadIdx.x, w = tid >> 6, lane = tid & 63;
    int c = lane & 15, g = lane >> 4;
    int lq = lane & 31, hh = lane >> 5;    // staging decomposition

    const unsigned short* Qg = qkv;
    const unsigned short* Kg = qkv + (size_t)Mn * Dn;
    const unsigned short* Vt = qkv + (size_t)2 * Mn * Dn;

    int qrow = q0 + w * 16;
    int qg_lane = qrow + c;

    // Q B-fragments: lane (c,g) holds Q[q=c][d=32kk+8g..+7]
    bf16x8 qf[8];
#pragma unroll
    for (int kk = 0; kk < 8; kk++)
        qf[kk] = *(const bf16x8*)(Qg + ((size_t)b * Tn + qrow + c) * Dn + kk * 32 + g * 8);

    const f32x4 fz = {0.f, 0.f, 0.f, 0.f};
    f32x4 o[16];
#pragma unroll
    for (int n = 0; n < 16; n++) o[n] = fz;
    float m2 = -INFINITY, l = 0.f;

    const float C1 = 0.09016844005555897f;   // (1/16) * log2(e)

    // ---- staging (round-5-verified patterns; pre-swizzled source, linear LDS dest) ----
    auto STAGE_K = [&](int cb, int t) {
        const unsigned short* kgb = Kg + ((size_t)b * Tn + t * 32) * Dn;
        char* kb = smem + cb * 16384 + w * 4096;
#pragma unroll
        for (int i = 0; i < 4; i++) {
            int row = w * 8 + i * 2 + hh;
            int chunk = lq ^ row;            // LDS slot s holds chunk s^row
            g2lds16(kgb + row * 256 + chunk * 8, kb + i * 1024);
        }
    };
    auto STAGE_V = [&](int t) {
        const unsigned short* vgb = Vt + (size_t)b * Tn + t * 32;
        char* vb = smem + 32768 + w * 4096;
#pragma unroll
        for (int i = 0; i < 4; i++) {
            int d = w * 64 + i * 16 + (lane >> 2);
            int kvc = (lane & 3) ^ ((d >> 3) & 3);   // slot s holds chunk s^swz
            g2lds16(vgb + (size_t)d * Mn + kvc * 8, vb + i * 1024);
        }
    };

    union U4 { unsigned int u[4]; bf16x8 v; };
    U4 pf;

    auto QKSM = [&](int cb, int t) {
        int kv0 = t * 32;
        const char* klds = smem + cb * 16384;
        // ---- S^T = K Q^T: two independent 8-chains (round-4 layout) ----
        f32x4 s0 = fz, s1 = fz;
        int r0 = c, r1 = 16 + c;
        __builtin_amdgcn_s_setprio(1);
#pragma unroll
        for (int kk = 0; kk < 8; kk++) {
            bf16x8 kf0 = *(const bf16x8*)(klds + r0 * 512 + (((4 * kk + g) ^ r0) * 16));
            s0 = __builtin_amdgcn_mfma_f32_16x16x32_bf16(kf0, qf[kk], s0, 0, 0, 0);
            bf16x8 kf1 = *(const bf16x8*)(klds + r1 * 512 + (((4 * kk + g) ^ r1) * 16));
            s1 = __builtin_amdgcn_mfma_f32_16x16x32_bf16(kf1, qf[kk], s1, 0, 0, 0);
        }
        __builtin_amdgcn_s_setprio(0);
        // ---- mask + scale (exp2 domain) ----
        float t2[2][4];
        float tmax = -INFINITY;
#pragma unroll
        for (int rr = 0; rr < 4; rr++) {
            float v0 = s0[rr] * C1, v1 = s1[rr] * C1;
            int kv_0 = kv0 + 4 * g + rr;
            v0 = (kv_0 <= qg_lane) ? v0 : -INFINITY;
            v1 = (kv_0 + 16 <= qg_lane) ? v1 : -INFINITY;
            t2[0][rr] = v0; t2[1][rr] = v1;
            tmax = fmaxf(tmax, fmaxf(v0, v1));
        }
        tmax = fmaxf(tmax, __shfl_xor(tmax, 16));
        tmax = fmaxf(tmax, __shfl_xor(tmax, 32));
        float mn = m2;
        if (!__all(tmax - m2 <= 8.0f)) {          // T13 defer-max
            mn = fmaxf(m2, tmax);
            float alpha = exp2f(m2 - mn);
            l *= alpha;
            m2 = mn;
#pragma unroll
            for (int n = 0; n < 16; n++) o[n] = o[n] * alpha;
        }
        float p[2][4];
        float ps = 0.f;
#pragma unroll
        for (int n = 0; n < 2; n++)
#pragma unroll
            for (int rr = 0; rr < 4; rr++) {
                float pv = exp2f(t2[n][rr] - mn);
                p[n][rr] = pv;
                ps += pv;
            }
        ps += __shfl_xor(ps, 16);
        ps += __shfl_xor(ps, 32);
        l += ps;
        // pack pairs: pk[n][hs] = {p[n][2hs], p[n][2hs+1]}  (kv = 16n + 4g' + 2hs, +1)
        unsigned int pk[2][2];
#pragma unroll
        for (int n = 0; n < 2; n++)
#pragma unroll
            for (int hs = 0; hs < 2; hs++)
                pk[n][hs] = pk2(p[n][2 * hs], p[n][2 * hs + 1]);
        // redistribute (round-4-verified): dest lane (c,g) word h = P[q=c][kv=8g+2h,+1];
        // gs = 2(g&1)+(h>>1); shfl with lane-uniform reg indices, dest-side n-half select
#pragma unroll
        for (int h = 0; h < 4; h++) {
            int gs = 2 * (g & 1) + (h >> 1);
            unsigned int lo = (unsigned int)__shfl((int)pk[0][h & 1], c + 16 * gs);
            unsigned int hi = (unsigned int)__shfl((int)pk[1][h & 1], c + 16 * gs);
            pf.u[h] = (g >= 2) ? hi : lo;
        }
    };

    auto PV = [&]() {
        const char* vlds = smem + 32768;
        __builtin_amdgcn_s_setprio(1);
#pragma unroll
        for (int n = 0; n < 16; n++) {
            int d = n * 16 + c;
            bf16x8 vf = *(const bf16x8*)(vlds + d * 64 + ((g ^ ((d >> 3) & 3)) * 16));
            o[n] = __builtin_amdgcn_mfma_f32_16x16x32_bf16(vf, pf.v, o[n], 0, 0, 0);
        }
        __builtin_amdgcn_s_setprio(0);
    };

    int t0 = cc * 32;
    int tend = min(t0 + 32, 2 * qt + 2);
    int cb = 0;
    STAGE_K(0, t0);
    STAGE_V(t0);
    __syncthreads();
    for (int t = t0; t < tend; t++) {
        if (t + 1 < tend) STAGE_K(cb ^ 1, t + 1);
        QKSM(cb, t);
        __syncthreads();          // drains V(t) (+K(t+1), covered by QK+softmax)
        PV();
        if (t + 1 < tend) {
            __syncthreads();      // V buffer free for overwrite
            STAGE_V(t + 1);
        }
        cb ^= 1;
    }

    // ---- write m,l ----
    if (g == 0)
        ml[slot * 64 + w * 16 + c] = make_float2(m2, l);

    // ---- epilogue: O^T -> row-major bf16 partial via per-wave LDS transpose (round 4) ----
    __syncthreads();
    float* eld = (float*)(smem + w * 4352);   // 16 rows x 68 f32
    int rql = lane >> 2, cg4 = lane & 3;
#pragma unroll
    for (int ch4 = 0; ch4 < 4; ch4++) {
#pragma unroll
        for (int nn = 0; nn < 4; nn++)
            *(f32x4*)(eld + c * 68 + nn * 16 + 4 * g) = o[ch4 * 4 + nn];
        asm volatile("s_waitcnt lgkmcnt(0)" ::: "memory");
        __builtin_amdgcn_sched_barrier(0);
#pragma unroll
        for (int k = 0; k < 4; k++) {
            f32x4 v = *(const f32x4*)(eld + rql * 68 + cg4 * 16 + 4 * k);
            union { unsigned short u[4]; ushort4 v4; } pkk;
            pkk.u[0] = f2bf(v[0]); pkk.u[1] = f2bf(v[1]);
            pkk.u[2] = f2bf(v[2]); pkk.u[3] = f2bf(v[3]);
            *(ushort4*)(part + ((size_t)slot * 64 + w * 16 + rql) * 256
                             + ch4 * 64 + cg4 * 16 + 4 * k) = pkk.v4;
        }
        asm volatile("s_waitcnt lgkmcnt(0)" ::: "memory");
        __builtin_amdgcn_sched_barrier(0);
    }
}

// ---------------- combine partials (round-4-verified) ----------------
__global__ void __launch_bounds__(256) combine_kernel(const unsigned short* __restrict__ part,
                                                      const float2* __restrict__ ml,
                                                      float* __restrict__ out) {
    int row = blockIdx.x * 4 + (threadIdx.x >> 6);
    int fi = (threadIdx.x & 63) * 4;
    int b = row >> 12, q = row & 4095;
    int qt = q >> 6, qloc = q & 63;
    int nch = (qt >> 4) + 1;
    const int offt[4] = {0, 64, 112, 144};
    int slots[4]; float mv[4], lv[4];
    float M = -INFINITY;
    for (int ci = 0; ci < nch; ci++) {
        int slot = b * 160 + offt[ci] + (63 - qt);
        slots[ci] = slot;
        float2 p = ml[slot * 64 + qloc];
        mv[ci] = p.x; lv[ci] = p.y;
        M = fmaxf(M, p.x);
    }
    float L = 0.f;
    float a0 = 0.f, a1 = 0.f, a2 = 0.f, a3 = 0.f;
    for (int ci = 0; ci < nch; ci++) {
        float wgt = exp2f(mv[ci] - M);
        L += wgt * lv[ci];
        ushort4 u = *(const ushort4*)(part + ((size_t)slots[ci] * 64 + qloc) * 256 + fi);
        a0 += wgt * bf2f(u.x); a1 += wgt * bf2f(u.y);
        a2 += wgt * bf2f(u.z); a3 += wgt * bf2f(u.w);
    }
    float inv = 1.f / L;
    float4 ov = {a0 * inv, a1 * inv, a2 * inv, a3 * inv};
    *(float4*)(out + (size_t)row * 256 + fi) = ov;
}

extern "C" void kernel_launch(void* const* d_in, const int* in_sizes, int n_in,
                              void* d_out, int out_size, void* d_ws, size_t ws_size,
                              hipStream_t stream) {
    (void)in_sizes; (void)n_in; (void)out_size; (void)ws_size;
    const float* x  = (const float*)d_in[0];
    const float* wk = (const float*)d_in[1];
    const float* wq = (const float*)d_in[2];
    const float* wv = (const float*)d_in[3];
    float* outp = (float*)d_out;

    char* ws = (char*)d_ws;
    unsigned short* wt   = (unsigned short*)(ws + WT_OFF);
    unsigned short* qkv  = (unsigned short*)(ws + QKV_OFF);
    unsigned short* part = (unsigned short*)(ws + P_OFF);
    float2*         mlp  = (float2*)(ws + ML_OFF);

    wt_kernel<<<3 * 65536 / 256, 256, 0, stream>>>(wq, wk, wv, wt);
    proj_kernel<<<dim3(Mn / 64, 3), 256, 0, stream>>>(x, wt, qkv);
    attn_kernel<<<1280, 256, 0, stream>>>(qkv, part, mlp);
    combine_kernel<<<Mn / 4, 256, 0, stream>>>(part, mlp, outp);
}